// Round 12
// baseline (227.340 us; speedup 1.0000x reference)
//
#include <hip/hip_runtime.h>
#include <hip/hip_fp16.h>

#define N_NODES 50000
#define N_EDGES 800000
#define D_FEAT 128
#define HEADS 8
#define UNITS 32
#define HU (HEADS * UNITS) /* 256 */
#define LEAKY 0.2f
#define EPSV 1e-7f
#define NBLK 196 /* ceil(50000/256) */

typedef _Float16 half8 __attribute__((ext_vector_type(8)));
typedef _Float16 half4 __attribute__((ext_vector_type(4)));
typedef float f32x4 __attribute__((ext_vector_type(4)));

struct h4pk { __half2 a, b; }; // 4 fp16 channels = 8 bytes

// ---- prep: W -> W^T fp16 (blocks 0..127) | 4-shadow in-degree counts ----
#define WBLK 128              /* 128*256 = 32768 = D_FEAT*HU */
#define EBLK 3125             /* 3125*256 = 800,000 = N_EDGES */
__global__ __launch_bounds__(256) void k_prep(const float* __restrict__ W,
                                              const int* __restrict__ edges,
                                              __half* __restrict__ Wt,
                                              int* __restrict__ counts4) {
    const int b = blockIdx.x, t = threadIdx.x;
    if (b < WBLK) {
        const int i = b * 256 + t;            // i = n*128 + k
        const int n = i >> 7, k = i & 127;
        Wt[i] = __float2half(W[k * HU + n]);  // Wt[n][k] = W[k][n]
    } else {
        const int e = (b - WBLK) * 256 + t;
        if (e < N_EDGES)
            atomicAdd(&counts4[(e & 3) * N_NODES + edges[2 * e + 1]], 1);
    }
}

// ---- hierarchical scan ----
__global__ __launch_bounds__(256) void k_scanA(const int* __restrict__ counts4,
                                               int* __restrict__ counts,
                                               int* __restrict__ partials) {
    const int i = blockIdx.x * 256 + threadIdx.x;
    int v = 0;
    if (i < N_NODES) {
        v = counts4[i] + counts4[N_NODES + i] + counts4[2 * N_NODES + i] + counts4[3 * N_NODES + i];
        counts[i] = v;
    }
#pragma unroll
    for (int m = 32; m >= 1; m >>= 1) v += __shfl_xor(v, m);
    __shared__ int ws[4];
    if ((threadIdx.x & 63) == 0) ws[threadIdx.x >> 6] = v;
    __syncthreads();
    if (threadIdx.x == 0) partials[blockIdx.x] = ws[0] + ws[1] + ws[2] + ws[3];
}

__global__ __launch_bounds__(256) void k_scanB(int* __restrict__ partials) {
    __shared__ int s[256];
    const int t = threadIdx.x;
    const int v = (t < NBLK) ? partials[t] : 0;
    s[t] = v;
    __syncthreads();
    for (int o = 1; o < 256; o <<= 1) {
        const int u = (t >= o) ? s[t - o] : 0;
        __syncthreads();
        s[t] += u;
        __syncthreads();
    }
    if (t < NBLK) partials[t] = s[t] - v; // exclusive
}

__global__ __launch_bounds__(256) void k_scanC(const int* __restrict__ counts,
                                               const int* __restrict__ partials,
                                               int* __restrict__ offs,
                                               int* __restrict__ cursor) {
    __shared__ int s[256];
    const int t = threadIdx.x;
    const int i = blockIdx.x * 256 + t;
    const int v = (i < N_NODES) ? counts[i] : 0;
    s[t] = v;
    __syncthreads();
    for (int o = 1; o < 256; o <<= 1) {
        const int u = (t >= o) ? s[t - o] : 0;
        __syncthreads();
        s[t] += u;
        __syncthreads();
    }
    if (i < N_NODES) {
        const int st = partials[blockIdx.x] + s[t] - v; // exclusive start
        offs[i] = st;
        cursor[i] = st;
    }
}

// ---- MEGA: gemm blocks [0,GEMM_BLOCKS) co-run with CSR-fill blocks.
// SINGLE CHANGE vs R11: __launch_bounds__(256, 1) -> allocator may use up
// to 512 VGPRs/lane, so acc[16] (64 fp32) stays in registers instead of
// spilling to scratch (the hypothesized source of the ~100 MB write-amp
// and ~25 MB fetch-amp seen in every MFMA variant, VGPR_Count 32-68).
#define XPAD 136 /* 128 + 8 halfs: bank-friendly row stride */
#define GEMM_BLOCKS 782 /* ceil(50000/64) */
__global__ __launch_bounds__(256, 1) void k_mega(const float* __restrict__ x,
                                                 const __half* __restrict__ Wt,
                                                 const float* __restrict__ ka1,
                                                 const int* __restrict__ edges,
                                                 int* __restrict__ cursor,
                                                 __half* __restrict__ h,
                                                 float* __restrict__ f,
                                                 int* __restrict__ elist) {
    __shared__ __align__(16) _Float16 xs[64 * XPAD]; // 17 KB
    if (blockIdx.x >= GEMM_BLOCKS) {
        // ---- fill branch ----
        const int e = (blockIdx.x - GEMM_BLOCKS) * 256 + threadIdx.x;
        if (e < N_EDGES) {
            const int2 st = reinterpret_cast<const int2*>(edges)[e];
            const int p = atomicAdd(&cursor[st.y], 1);
            elist[p] = st.x;
        }
        return;
    }
    // ---- gemm branch ----
    const int tid = threadIdx.x;
    const int wid = tid >> 6, l = tid & 63;
    const int row16 = l & 15, kg = l >> 4;
    const int rbase = blockIdx.x * 64;

    // stage 64 rows x 128 cols of x, fp32 -> fp16, fully coalesced reads
#pragma unroll
    for (int i = 0; i < 8; ++i) {
        const int flat = (i * 256 + tid) * 4;  // element in 64x128 tile
        const int row = flat >> 7, col = flat & 127;
        const int gr = min(rbase + row, N_NODES - 1);
        const float4 v = *reinterpret_cast<const float4*>(x + (size_t)gr * D_FEAT + col);
        half4 hv;
        hv[0] = (_Float16)v.x; hv[1] = (_Float16)v.y;
        hv[2] = (_Float16)v.z; hv[3] = (_Float16)v.w;
        *reinterpret_cast<half4*>(&xs[row * XPAD + col]) = hv;
    }
    __syncthreads();

    // A fragments: wave wid owns rows wid*16 .. +15
    half8 a[4];
    const int arow = wid * 16 + row16;
#pragma unroll
    for (int ks = 0; ks < 4; ++ks)
        a[ks] = *reinterpret_cast<const half8*>(&xs[arow * XPAD + ks * 32 + kg * 8]);

    f32x4 acc[16];
#pragma unroll
    for (int ct = 0; ct < 16; ++ct) acc[ct] = (f32x4){0.f, 0.f, 0.f, 0.f};

#pragma unroll 4
    for (int ct = 0; ct < 16; ++ct) {
        const __half* wp = Wt + (ct * 16 + row16) * D_FEAT + kg * 8;
#pragma unroll
        for (int ks = 0; ks < 4; ++ks) {
            const half8 bf = *reinterpret_cast<const half8*>(wp + ks * 32);
            acc[ct] = __builtin_amdgcn_mfma_f32_16x16x32_f16(a[ks], bf, acc[ct], 0, 0, 0);
        }
    }

    const int wrbase = rbase + wid * 16;
    // h writeback: direct scalar 2B stores from acc (C/D layout:
    // col = ct*16+row16, row = kg*4+r). Adjacent ct completes 64B lines.
#pragma unroll
    for (int ct = 0; ct < 16; ++ct) {
        const int col = ct * 16 + row16;
#pragma unroll
        for (int r = 0; r < 4; ++r) {
            const int hr = wrbase + kg * 4 + r;
            if (hr < N_NODES)
                h[(size_t)hr * HU + col] = __float2half(acc[ct][r]);
        }
    }

    // f[row][hd] = sum_col h[row][col]*ka1[col] from fp32 acc via shfl-reduce
#pragma unroll
    for (int hd = 0; hd < 8; ++hd) {
        const float ka = ka1[hd * 32 + row16];
        const float kb = ka1[hd * 32 + 16 + row16];
#pragma unroll
        for (int r = 0; r < 4; ++r) {
            float v = acc[2 * hd][r] * ka + acc[2 * hd + 1][r] * kb;
            v += __shfl_xor(v, 1);
            v += __shfl_xor(v, 2);
            v += __shfl_xor(v, 4);
            v += __shfl_xor(v, 8);
            if (row16 == 0) {
                const int hr = wrbase + kg * 4 + r;
                if (hr < N_NODES) f[(size_t)hr * HEADS + hd] = v;
            }
        }
    }
}

// ---- g[v] = f[targets[v]]  (reference quirk: f_s = f_t[sources]) ----
__global__ __launch_bounds__(256) void k_g(const int* __restrict__ edges,
                                           const float* __restrict__ f,
                                           float* __restrict__ g) {
    const int v = blockIdx.x * 256 + threadIdx.x;
    if (v >= N_NODES) return;
    const int t2 = edges[2 * v + 1];
    const float4 A = *reinterpret_cast<const float4*>(f + (size_t)t2 * HEADS);
    const float4 B = *reinterpret_cast<const float4*>(f + (size_t)t2 * HEADS + 4);
    *reinterpret_cast<float4*>(g + (size_t)v * HEADS) = A;
    *reinterpret_cast<float4*>(g + (size_t)v * HEADS + 4) = B;
}

// ---- single sweep, no-max softmax (safe: z <= ~8 << 88) + weighted gather ----
__global__ __launch_bounds__(256) void k_out(const __half* __restrict__ h,
                                             const int* __restrict__ elist,
                                             const float* __restrict__ f,
                                             const float* __restrict__ g,
                                             const int* __restrict__ offs, // segment START
                                             const int* __restrict__ counts,
                                             const float* __restrict__ bias,
                                             float* __restrict__ out,
                                             int nbase, int ncount) {
    const int ni = blockIdx.x * 4 + (threadIdx.x >> 6);
    if (ni >= ncount) return;
    const int n = nbase + ni;
    const int lane = threadIdx.x & 63;
    const int head = lane >> 3;
    const int c4 = lane * 4;
    const int start = offs[n];
    const int end = start + counts[n];
    const float fn = f[(size_t)n * HEADS + head];

    float d = 0.f;
    float4 acc = make_float4(0.f, 0.f, 0.f, 0.f);

    int p = start;
    for (; p + 4 <= end; p += 4) {
        const int s0 = elist[p + 0];
        const int s1 = elist[p + 1];
        const int s2 = elist[p + 2];
        const int s3 = elist[p + 3];
        const float gz0 = g[(size_t)s0 * HEADS + head];
        const float gz1 = g[(size_t)s1 * HEADS + head];
        const float gz2 = g[(size_t)s2 * HEADS + head];
        const float gz3 = g[(size_t)s3 * HEADS + head];
        const h4pk hv0 = *reinterpret_cast<const h4pk*>(h + (size_t)s0 * HU + c4);
        const h4pk hv1 = *reinterpret_cast<const h4pk*>(h + (size_t)s1 * HU + c4);
        const h4pk hv2 = *reinterpret_cast<const h4pk*>(h + (size_t)s2 * HU + c4);
        const h4pk hv3 = *reinterpret_cast<const h4pk*>(h + (size_t)s3 * HU + c4);

        float z0 = fn + gz0; z0 = (z0 > 0.f) ? z0 : LEAKY * z0;
        float z1 = fn + gz1; z1 = (z1 > 0.f) ? z1 : LEAKY * z1;
        float z2 = fn + gz2; z2 = (z2 > 0.f) ? z2 : LEAKY * z2;
        float z3 = fn + gz3; z3 = (z3 > 0.f) ? z3 : LEAKY * z3;
        const float w0 = __expf(z0);
        const float w1 = __expf(z1);
        const float w2 = __expf(z2);
        const float w3 = __expf(z3);
        d += (w0 + w1) + (w2 + w3);

        float2 fa, fb;
        fa = __half22float2(hv0.a); fb = __half22float2(hv0.b);
        acc.x += w0 * fa.x; acc.y += w0 * fa.y; acc.z += w0 * fb.x; acc.w += w0 * fb.y;
        fa = __half22float2(hv1.a); fb = __half22float2(hv1.b);
        acc.x += w1 * fa.x; acc.y += w1 * fa.y; acc.z += w1 * fb.x; acc.w += w1 * fb.y;
        fa = __half22float2(hv2.a); fb = __half22float2(hv2.b);
        acc.x += w2 * fa.x; acc.y += w2 * fa.y; acc.z += w2 * fb.x; acc.w += w2 * fb.y;
        fa = __half22float2(hv3.a); fb = __half22float2(hv3.b);
        acc.x += w3 * fa.x; acc.y += w3 * fa.y; acc.z += w3 * fb.x; acc.w += w3 * fb.y;
    }
    for (; p < end; ++p) {
        const int s = elist[p];
        float z = fn + g[(size_t)s * HEADS + head];
        z = (z > 0.f) ? z : LEAKY * z;
        const float w = __expf(z);
        const h4pk hv = *reinterpret_cast<const h4pk*>(h + (size_t)s * HU + c4);
        const float2 fa = __half22float2(hv.a);
        const float2 fb = __half22float2(hv.b);
        d += w;
        acc.x += w * fa.x;
        acc.y += w * fa.y;
        acc.z += w * fb.x;
        acc.w += w * fb.y;
    }

    const float inv = 1.f / (d + EPSV);
    const float4 b = *reinterpret_cast<const float4*>(bias + c4);
    float v;
    float4 o;
    v = acc.x * inv + b.x; o.x = (v > 0.f) ? v : expm1f(v);
    v = acc.y * inv + b.y; o.y = (v > 0.f) ? v : expm1f(v);
    v = acc.z * inv + b.z; o.z = (v > 0.f) ? v : expm1f(v);
    v = acc.w * inv + b.w; o.w = (v > 0.f) ? v : expm1f(v);
    *reinterpret_cast<float4*>(out + (size_t)n * HU + c4) = o;
}

extern "C" void kernel_launch(void* const* d_in, const int* in_sizes, int n_in,
                              void* d_out, int out_size, void* d_ws, size_t ws_size,
                              hipStream_t stream) {
    const float* x = (const float*)d_in[0];
    const int* edges = (const int*)d_in[1];
    const float* W = (const float*)d_in[2];
    const float* ka1 = (const float*)d_in[3];
    // d_in[4] = ka2: unused by the reference
    const float* bias = (const float*)d_in[5];
    float* out = (float*)d_out;

    char* ws = (char*)d_ws;
    size_t off = 0;
    auto alloc = [&](size_t bytes) -> void* {
        void* p = ws + off;
        off = (off + bytes + 255) & ~size_t(255);
        return p;
    };
    __half* h = (__half*)alloc(sizeof(__half) * (size_t)N_NODES * HU); // 25.6 MB
    __half* Wt = (__half*)alloc(sizeof(__half) * D_FEAT * HU);         // 64 KB
    float* f = (float*)alloc(sizeof(float) * N_NODES * HEADS);         // 1.6 MB
    float* g = (float*)alloc(sizeof(float) * N_NODES * HEADS);         // 1.6 MB
    int* counts4 = (int*)alloc(sizeof(int) * 4 * N_NODES);             // 800 KB
    int* counts = (int*)alloc(sizeof(int) * N_NODES);
    int* offs = (int*)alloc(sizeof(int) * N_NODES);
    int* cursor = (int*)alloc(sizeof(int) * N_NODES);
    int* partials = (int*)alloc(sizeof(int) * NBLK);
    int* elist = (int*)alloc(sizeof(int) * N_EDGES);                   // 3.2 MB

    hipMemsetAsync(counts4, 0, sizeof(int) * 4 * N_NODES, stream);

    k_prep<<<WBLK + EBLK, 256, 0, stream>>>(W, edges, Wt, counts4);
    k_scanA<<<NBLK, 256, 0, stream>>>(counts4, counts, partials);
    k_scanB<<<1, 256, 0, stream>>>(partials);
    k_scanC<<<NBLK, 256, 0, stream>>>(counts, partials, offs, cursor);
    k_mega<<<GEMM_BLOCKS + EBLK, 256, 0, stream>>>(x, Wt, ka1, edges, cursor, h, f, elist);
    k_g<<<NBLK, 256, 0, stream>>>(edges, f, g);
    k_out<<<(25000 + 3) / 4, 256, 0, stream>>>(h, elist, f, g, offs, counts, bias, out, 0, 25000);
    k_out<<<(25000 + 3) / 4, 256, 0, stream>>>(h, elist, f, g, offs, counts, bias, out, 25000, 25000);
}

// Round 13
// 224.448 us; speedup vs baseline: 1.0129x; 1.0129x over previous
//
#include <hip/hip_runtime.h>
#include <hip/hip_fp16.h>

#define N_NODES 50000
#define N_EDGES 800000
#define D_FEAT 128
#define HEADS 8
#define UNITS 32
#define HU (HEADS * UNITS) /* 256 */
#define LEAKY 0.2f
#define EPSV 1e-7f
#define NBLK 196 /* ceil(50000/256) */

typedef _Float16 half8 __attribute__((ext_vector_type(8)));
typedef float f32x4 __attribute__((ext_vector_type(4)));

struct h4pk { __half2 a, b; }; // 4 fp16 channels = 8 bytes

// ---- fused: x fp32->fp16 | W -> W^T fp16 | in-degree counts (R7 verbatim) ----
#define XBLK 3125             /* 3125*256*8 = 6,400,000 = N_NODES*D_FEAT */
#define WBLK 128              /* 128*256 = 32768 = D_FEAT*HU */
#define EBLK 3125             /* 3125*256 = 800,000 = N_EDGES */
__global__ __launch_bounds__(256) void k_conv(const float* __restrict__ x,
                                              const float* __restrict__ W,
                                              const int* __restrict__ edges,
                                              __half* __restrict__ x16,
                                              __half* __restrict__ Wt,
                                              int* __restrict__ counts) {
    const int b = blockIdx.x, t = threadIdx.x;
    if (b < XBLK) {
        const int i = (b * 256 + t) * 8;
        const float4 v0 = *reinterpret_cast<const float4*>(x + i);
        const float4 v1 = *reinterpret_cast<const float4*>(x + i + 4);
        half8 o;
        o[0] = (_Float16)v0.x; o[1] = (_Float16)v0.y;
        o[2] = (_Float16)v0.z; o[3] = (_Float16)v0.w;
        o[4] = (_Float16)v1.x; o[5] = (_Float16)v1.y;
        o[6] = (_Float16)v1.z; o[7] = (_Float16)v1.w;
        *reinterpret_cast<half8*>(x16 + i) = o;
    } else if (b < XBLK + WBLK) {
        const int i = (b - XBLK) * 256 + t;   // i = n*128 + k
        const int n = i >> 7, k = i & 127;
        Wt[i] = __float2half(W[k * HU + n]);  // Wt[n][k] = W[k][n]
    } else {
        const int e = (b - XBLK - WBLK) * 256 + t;
        if (e < N_EDGES) atomicAdd(&counts[edges[2 * e + 1]], 1);
    }
}

// ---- MFMA GEMM (R7 verbatim): h(fp16) = x16 @ Wt^T, fused f ----
__global__ __launch_bounds__(64) void k_gemm(const __half* __restrict__ x16,
                                             const __half* __restrict__ Wt,
                                             const float* __restrict__ ka1,
                                             __half* __restrict__ h,
                                             float* __restrict__ f) {
    __shared__ __align__(16) __half hs[16 * HU]; // 8 KB
    const int l = threadIdx.x;
    const int row16 = l & 15, kg = l >> 4;
    const size_t rbase = (size_t)blockIdx.x * 16;

    half8 a[4];
#pragma unroll
    for (int ks = 0; ks < 4; ++ks)
        a[ks] = *reinterpret_cast<const half8*>(x16 + (rbase + row16) * D_FEAT + ks * 32 + kg * 8);

    f32x4 acc[16];
#pragma unroll
    for (int ct = 0; ct < 16; ++ct) acc[ct] = (f32x4){0.f, 0.f, 0.f, 0.f};

#pragma unroll
    for (int ct = 0; ct < 16; ++ct) {
        const __half* wp = Wt + (ct * 16 + row16) * D_FEAT + kg * 8;
#pragma unroll
        for (int ks = 0; ks < 4; ++ks) {
            const half8 bf = *reinterpret_cast<const half8*>(wp + ks * 32);
            acc[ct] = __builtin_amdgcn_mfma_f32_16x16x32_f16(a[ks], bf, acc[ct], 0, 0, 0);
        }
    }

#pragma unroll
    for (int ct = 0; ct < 16; ++ct) {
        const int col = ct * 16 + row16;
#pragma unroll
        for (int r = 0; r < 4; ++r)
            hs[(kg * 4 + r) * HU + col] = __float2half(acc[ct][r]);
    }
    __syncthreads();

#pragma unroll
    for (int j = 0; j < 8; ++j) {
        const int slot = j * 64 + l;
        const half8 v = *reinterpret_cast<const half8*>(hs + slot * 8);
        *reinterpret_cast<half8*>(h + rbase * HU + slot * 8) = v;
    }

#pragma unroll
    for (int hf = 0; hf < 2; ++hf) {
        const int o = hf * 64 + l;
        const int row = o >> 3, hd = o & 7;
        const __half* hp = hs + row * HU + hd * UNITS;
        const float* kp = ka1 + hd * UNITS;
        float s = 0.f;
#pragma unroll
        for (int u = 0; u < UNITS; u += 8) {
            const half8 hv = *reinterpret_cast<const half8*>(hp + u);
            const float4 k0 = *reinterpret_cast<const float4*>(kp + u);
            const float4 k1 = *reinterpret_cast<const float4*>(kp + u + 4);
            s += (float)hv[0] * k0.x + (float)hv[1] * k0.y + (float)hv[2] * k0.z + (float)hv[3] * k0.w;
            s += (float)hv[4] * k1.x + (float)hv[5] * k1.y + (float)hv[6] * k1.z + (float)hv[7] * k1.w;
        }
        f[rbase * HEADS + o] = s;
    }
}

// ---- hierarchical scan; scanC also emits cursor + g-gather ----
__global__ __launch_bounds__(256) void k_scanA(const int* __restrict__ counts,
                                               int* __restrict__ partials) {
    const int i = blockIdx.x * 256 + threadIdx.x;
    int v = (i < N_NODES) ? counts[i] : 0;
#pragma unroll
    for (int m = 32; m >= 1; m >>= 1) v += __shfl_xor(v, m);
    __shared__ int ws[4];
    if ((threadIdx.x & 63) == 0) ws[threadIdx.x >> 6] = v;
    __syncthreads();
    if (threadIdx.x == 0) partials[blockIdx.x] = ws[0] + ws[1] + ws[2] + ws[3];
}

__global__ __launch_bounds__(256) void k_scanB(int* __restrict__ partials) {
    __shared__ int s[256];
    const int t = threadIdx.x;
    const int v = (t < NBLK) ? partials[t] : 0;
    s[t] = v;
    __syncthreads();
    for (int o = 1; o < 256; o <<= 1) {
        const int u = (t >= o) ? s[t - o] : 0;
        __syncthreads();
        s[t] += u;
        __syncthreads();
    }
    if (t < NBLK) partials[t] = s[t] - v; // exclusive
}

__global__ __launch_bounds__(256) void k_scanC(const int* __restrict__ counts,
                                               const int* __restrict__ partials,
                                               const int* __restrict__ edges,
                                               const float* __restrict__ f,
                                               int* __restrict__ offs,
                                               int* __restrict__ cursor,
                                               float* __restrict__ g) {
    __shared__ int s[256];
    const int t = threadIdx.x;
    const int i = blockIdx.x * 256 + t;
    const int v = (i < N_NODES) ? counts[i] : 0;
    s[t] = v;
    __syncthreads();
    for (int o = 1; o < 256; o <<= 1) {
        const int u = (t >= o) ? s[t - o] : 0;
        __syncthreads();
        s[t] += u;
        __syncthreads();
    }
    if (i < N_NODES) {
        const int st = partials[blockIdx.x] + s[t] - v; // exclusive start
        offs[i] = st;
        cursor[i] = st;
        const int t2 = edges[2 * i + 1]; // quirk: f_s = f_t[sources]
        const float4 A = *reinterpret_cast<const float4*>(f + (size_t)t2 * HEADS);
        const float4 B = *reinterpret_cast<const float4*>(f + (size_t)t2 * HEADS + 4);
        *reinterpret_cast<float4*>(g + (size_t)i * HEADS) = A;
        *reinterpret_cast<float4*>(g + (size_t)i * HEADS + 4) = B;
    }
}

// ---- class-partitioned CSR fill: class = offs[target]/100000 selects one
// of 8 contiguous elist regions; blockIdx&7 -> XCD round-robin pins each
// region's dirty lines to one L2 (no cross-XCD partial-line writebacks).
__global__ __launch_bounds__(256) void k_fill(const int* __restrict__ edges,
                                              const int* __restrict__ offs,
                                              int* __restrict__ cursor,
                                              int* __restrict__ elist) {
    const int b = blockIdx.x;
    const int cls = b & 7;
    const int e = (b >> 3) * 256 + threadIdx.x;
    if (e >= N_EDGES) return;
    const int2 st = reinterpret_cast<const int2*>(edges)[e];
    const int cl = offs[st.y] / (N_EDGES / 8); // 100000 per class
    if (cl != cls) return;
    const int p = atomicAdd(&cursor[st.y], 1);
    elist[p] = st.x;
}

// ---- single sweep, no-max softmax (safe: z <= ~8 << 88) + weighted gather ----
__global__ __launch_bounds__(256) void k_out(const __half* __restrict__ h,
                                             const int* __restrict__ elist,
                                             const float* __restrict__ f,
                                             const float* __restrict__ g,
                                             const int* __restrict__ offs, // segment START
                                             const int* __restrict__ counts,
                                             const float* __restrict__ bias,
                                             float* __restrict__ out,
                                             int nbase, int ncount) {
    const int ni = blockIdx.x * 4 + (threadIdx.x >> 6);
    if (ni >= ncount) return;
    const int n = nbase + ni;
    const int lane = threadIdx.x & 63;
    const int head = lane >> 3;
    const int c4 = lane * 4;
    const int start = offs[n];
    const int end = start + counts[n];
    const float fn = f[(size_t)n * HEADS + head];

    float d = 0.f;
    float4 acc = make_float4(0.f, 0.f, 0.f, 0.f);

    int p = start;
    for (; p + 4 <= end; p += 4) {
        const int s0 = elist[p + 0];
        const int s1 = elist[p + 1];
        const int s2 = elist[p + 2];
        const int s3 = elist[p + 3];
        const float gz0 = g[(size_t)s0 * HEADS + head];
        const float gz1 = g[(size_t)s1 * HEADS + head];
        const float gz2 = g[(size_t)s2 * HEADS + head];
        const float gz3 = g[(size_t)s3 * HEADS + head];
        const h4pk hv0 = *reinterpret_cast<const h4pk*>(h + (size_t)s0 * HU + c4);
        const h4pk hv1 = *reinterpret_cast<const h4pk*>(h + (size_t)s1 * HU + c4);
        const h4pk hv2 = *reinterpret_cast<const h4pk*>(h + (size_t)s2 * HU + c4);
        const h4pk hv3 = *reinterpret_cast<const h4pk*>(h + (size_t)s3 * HU + c4);

        float z0 = fn + gz0; z0 = (z0 > 0.f) ? z0 : LEAKY * z0;
        float z1 = fn + gz1; z1 = (z1 > 0.f) ? z1 : LEAKY * z1;
        float z2 = fn + gz2; z2 = (z2 > 0.f) ? z2 : LEAKY * z2;
        float z3 = fn + gz3; z3 = (z3 > 0.f) ? z3 : LEAKY * z3;
        const float w0 = __expf(z0);
        const float w1 = __expf(z1);
        const float w2 = __expf(z2);
        const float w3 = __expf(z3);
        d += (w0 + w1) + (w2 + w3);

        float2 fa, fb;
        fa = __half22float2(hv0.a); fb = __half22float2(hv0.b);
        acc.x += w0 * fa.x; acc.y += w0 * fa.y; acc.z += w0 * fb.x; acc.w += w0 * fb.y;
        fa = __half22float2(hv1.a); fb = __half22float2(hv1.b);
        acc.x += w1 * fa.x; acc.y += w1 * fa.y; acc.z += w1 * fb.x; acc.w += w1 * fb.y;
        fa = __half22float2(hv2.a); fb = __half22float2(hv2.b);
        acc.x += w2 * fa.x; acc.y += w2 * fa.y; acc.z += w2 * fb.x; acc.w += w2 * fb.y;
        fa = __half22float2(hv3.a); fb = __half22float2(hv3.b);
        acc.x += w3 * fa.x; acc.y += w3 * fa.y; acc.z += w3 * fb.x; acc.w += w3 * fb.y;
    }
    for (; p < end; ++p) {
        const int s = elist[p];
        float z = fn + g[(size_t)s * HEADS + head];
        z = (z > 0.f) ? z : LEAKY * z;
        const float w = __expf(z);
        const h4pk hv = *reinterpret_cast<const h4pk*>(h + (size_t)s * HU + c4);
        const float2 fa = __half22float2(hv.a);
        const float2 fb = __half22float2(hv.b);
        d += w;
        acc.x += w * fa.x;
        acc.y += w * fa.y;
        acc.z += w * fb.x;
        acc.w += w * fb.y;
    }

    const float inv = 1.f / (d + EPSV);
    const float4 b = *reinterpret_cast<const float4*>(bias + c4);
    float v;
    float4 o;
    v = acc.x * inv + b.x; o.x = (v > 0.f) ? v : expm1f(v);
    v = acc.y * inv + b.y; o.y = (v > 0.f) ? v : expm1f(v);
    v = acc.z * inv + b.z; o.z = (v > 0.f) ? v : expm1f(v);
    v = acc.w * inv + b.w; o.w = (v > 0.f) ? v : expm1f(v);
    *reinterpret_cast<float4*>(out + (size_t)n * HU + c4) = o;
}

extern "C" void kernel_launch(void* const* d_in, const int* in_sizes, int n_in,
                              void* d_out, int out_size, void* d_ws, size_t ws_size,
                              hipStream_t stream) {
    const float* x = (const float*)d_in[0];
    const int* edges = (const int*)d_in[1];
    const float* W = (const float*)d_in[2];
    const float* ka1 = (const float*)d_in[3];
    // d_in[4] = ka2: unused by the reference
    const float* bias = (const float*)d_in[5];
    float* out = (float*)d_out;

    char* ws = (char*)d_ws;
    size_t off = 0;
    auto alloc = [&](size_t bytes) -> void* {
        void* p = ws + off;
        off = (off + bytes + 255) & ~size_t(255);
        return p;
    };
    __half* h = (__half*)alloc(sizeof(__half) * (size_t)N_NODES * HU);       // 25.6 MB
    __half* x16 = (__half*)alloc(sizeof(__half) * (size_t)N_NODES * D_FEAT); // 12.8 MB
    __half* Wt = (__half*)alloc(sizeof(__half) * D_FEAT * HU);               // 64 KB
    float* f = (float*)alloc(sizeof(float) * N_NODES * HEADS);               // 1.6 MB
    float* g = (float*)alloc(sizeof(float) * N_NODES * HEADS);               // 1.6 MB
    int* counts = (int*)alloc(sizeof(int) * N_NODES);
    int* offs = (int*)alloc(sizeof(int) * N_NODES);
    int* cursor = (int*)alloc(sizeof(int) * N_NODES);
    int* partials = (int*)alloc(sizeof(int) * NBLK);
    int* elist = (int*)alloc(sizeof(int) * N_EDGES);                         // 3.2 MB

    hipMemsetAsync(counts, 0, sizeof(int) * N_NODES, stream);

    k_conv<<<XBLK + WBLK + EBLK, 256, 0, stream>>>(x, W, edges, x16, Wt, counts);
    k_gemm<<<N_NODES / 16, 64, 0, stream>>>(x16, Wt, ka1, h, f);
    k_scanA<<<NBLK, 256, 0, stream>>>(counts, partials);
    k_scanB<<<1, 256, 0, stream>>>(partials);
    k_scanC<<<NBLK, 256, 0, stream>>>(counts, partials, edges, f, offs, cursor, g);
    k_fill<<<8 * EBLK, 256, 0, stream>>>(edges, offs, cursor, elist);
    k_out<<<(25000 + 3) / 4, 256, 0, stream>>>(h, elist, f, g, offs, counts, bias, out, 0, 25000);
    k_out<<<(25000 + 3) / 4, 256, 0, stream>>>(h, elist, f, g, offs, counts, bias, out, 25000, 25000);
}

// Round 14
// 201.290 us; speedup vs baseline: 1.1294x; 1.1150x over previous
//
#include <hip/hip_runtime.h>
#include <hip/hip_fp16.h>

#define N_NODES 50000
#define N_EDGES 800000
#define D_FEAT 128
#define HEADS 8
#define UNITS 32
#define HU (HEADS * UNITS) /* 256 */
#define LEAKY 0.2f
#define EPSV 1e-7f
#define NBLK 196 /* ceil(50000/256) */
#define HSP 258 /* padded LDS row stride in halfs: bank-conflict-free */

typedef _Float16 half8 __attribute__((ext_vector_type(8)));
typedef float f32x4 __attribute__((ext_vector_type(4)));

struct h4pk { __half2 a, b; }; // 4 fp16 channels = 8 bytes

// ---- prep: W -> W^T fp16 | in-degree counts (x conversion now in k_gemm) ----
#define WBLK 128              /* 128*256 = 32768 = D_FEAT*HU */
#define EBLK 3125             /* 3125*256 = 800,000 = N_EDGES */
__global__ __launch_bounds__(256) void k_conv(const float* __restrict__ W,
                                              const int* __restrict__ edges,
                                              __half* __restrict__ Wt,
                                              int* __restrict__ counts) {
    const int b = blockIdx.x, t = threadIdx.x;
    if (b < WBLK) {
        const int i = b * 256 + t;            // i = n*128 + k
        const int n = i >> 7, k = i & 127;
        Wt[i] = __float2half(W[k * HU + n]);  // Wt[n][k] = W[k][n]
    } else {
        const int e = (b - WBLK) * 256 + t;
        if (e < N_EDGES) atomicAdd(&counts[edges[2 * e + 1]], 1);
    }
}

// ---- MFMA GEMM: 1 wave / 32 rows (2 tiles). B-frag loaded once per ct,
// reused for both tiles (halves Wt L2 traffic, 2x MFMA ILP). x read fp32
// directly, converted in-register (x16 buffer eliminated). Padded LDS
// epilogue (HSP=258 -> all 32 banks, <=2-way).
__global__ __launch_bounds__(64) void k_gemm(const float* __restrict__ x,
                                             const __half* __restrict__ Wt,
                                             const float* __restrict__ ka1,
                                             __half* __restrict__ h,
                                             float* __restrict__ f) {
    __shared__ __align__(16) _Float16 hs[16 * HSP]; // 8.1 KB
    const int l = threadIdx.x;
    const int row16 = l & 15, kg = l >> 4;
    const int rbase = blockIdx.x * 32;

    // A fragments for both tiles: fp32 loads, in-register convert
    half8 a0[4], a1[4];
    const int r0 = min(rbase + row16, N_NODES - 1);
    const int r1 = min(rbase + 16 + row16, N_NODES - 1);
    const float* xp0 = x + (size_t)r0 * D_FEAT + kg * 8;
    const float* xp1 = x + (size_t)r1 * D_FEAT + kg * 8;
#pragma unroll
    for (int ks = 0; ks < 4; ++ks) {
        const float4 u0 = *reinterpret_cast<const float4*>(xp0 + ks * 32);
        const float4 v0 = *reinterpret_cast<const float4*>(xp0 + ks * 32 + 4);
        const float4 u1 = *reinterpret_cast<const float4*>(xp1 + ks * 32);
        const float4 v1 = *reinterpret_cast<const float4*>(xp1 + ks * 32 + 4);
        half8 t0, t1;
        t0[0] = (_Float16)u0.x; t0[1] = (_Float16)u0.y; t0[2] = (_Float16)u0.z; t0[3] = (_Float16)u0.w;
        t0[4] = (_Float16)v0.x; t0[5] = (_Float16)v0.y; t0[6] = (_Float16)v0.z; t0[7] = (_Float16)v0.w;
        t1[0] = (_Float16)u1.x; t1[1] = (_Float16)u1.y; t1[2] = (_Float16)u1.z; t1[3] = (_Float16)u1.w;
        t1[4] = (_Float16)v1.x; t1[5] = (_Float16)v1.y; t1[6] = (_Float16)v1.z; t1[7] = (_Float16)v1.w;
        a0[ks] = t0; a1[ks] = t1;
    }

    f32x4 acc0[16], acc1[16];
#pragma unroll
    for (int ct = 0; ct < 16; ++ct) {
        acc0[ct] = (f32x4){0.f, 0.f, 0.f, 0.f};
        acc1[ct] = (f32x4){0.f, 0.f, 0.f, 0.f};
    }

#pragma unroll
    for (int ct = 0; ct < 16; ++ct) {
        const __half* wp = Wt + (ct * 16 + row16) * D_FEAT + kg * 8;
#pragma unroll
        for (int ks = 0; ks < 4; ++ks) {
            const half8 bf = *reinterpret_cast<const half8*>(wp + ks * 32);
            acc0[ct] = __builtin_amdgcn_mfma_f32_16x16x32_f16(a0[ks], bf, acc0[ct], 0, 0, 0);
            acc1[ct] = __builtin_amdgcn_mfma_f32_16x16x32_f16(a1[ks], bf, acc1[ct], 0, 0, 0);
        }
    }

    // epilogue per tile through padded LDS (single-wave block: barriers cheap)
#pragma unroll
    for (int tile = 0; tile < 2; ++tile) {
        const int rb2 = rbase + tile * 16;
#pragma unroll
        for (int ct = 0; ct < 16; ++ct) {
            const int col = ct * 16 + row16;
#pragma unroll
            for (int r = 0; r < 4; ++r) {
                const f32x4 av = tile ? acc1[ct] : acc0[ct];
                hs[(kg * 4 + r) * HSP + col] = (_Float16)av[r];
            }
        }
        __syncthreads();

        // coalesced h writeback: 16 rows x 32 half8
#pragma unroll
        for (int j = 0; j < 8; ++j) {
            const int slot = j * 64 + l;
            const int row = slot >> 5, c8 = slot & 31;
            if (rb2 + row < N_NODES) {
                const half8 v = *reinterpret_cast<const half8*>(&hs[row * HSP + c8 * 8]);
                *reinterpret_cast<half8*>(h + (size_t)(rb2 + row) * HU + c8 * 8) = v;
            }
        }

        // f[row][hd] from staged tile
#pragma unroll
        for (int hf = 0; hf < 2; ++hf) {
            const int o = hf * 64 + l;
            const int row = o >> 3, hd = o & 7;
            if (rb2 + row < N_NODES) {
                const _Float16* hp = &hs[row * HSP + hd * UNITS];
                const float* kp = ka1 + hd * UNITS;
                float s = 0.f;
#pragma unroll
                for (int u = 0; u < UNITS; u += 8) {
                    const half8 hv = *reinterpret_cast<const half8*>(hp + u);
                    const float4 k0 = *reinterpret_cast<const float4*>(kp + u);
                    const float4 k1 = *reinterpret_cast<const float4*>(kp + u + 4);
                    s += (float)hv[0] * k0.x + (float)hv[1] * k0.y + (float)hv[2] * k0.z + (float)hv[3] * k0.w;
                    s += (float)hv[4] * k1.x + (float)hv[5] * k1.y + (float)hv[6] * k1.z + (float)hv[7] * k1.w;
                }
                f[(size_t)rb2 * HEADS + o] = s;
            }
        }
        __syncthreads(); // hs reused by next tile
    }
}

// ---- hierarchical scan; scanC also emits cursor + g-gather ----
__global__ __launch_bounds__(256) void k_scanA(const int* __restrict__ counts,
                                               int* __restrict__ partials) {
    const int i = blockIdx.x * 256 + threadIdx.x;
    int v = (i < N_NODES) ? counts[i] : 0;
#pragma unroll
    for (int m = 32; m >= 1; m >>= 1) v += __shfl_xor(v, m);
    __shared__ int ws[4];
    if ((threadIdx.x & 63) == 0) ws[threadIdx.x >> 6] = v;
    __syncthreads();
    if (threadIdx.x == 0) partials[blockIdx.x] = ws[0] + ws[1] + ws[2] + ws[3];
}

__global__ __launch_bounds__(256) void k_scanB(int* __restrict__ partials) {
    __shared__ int s[256];
    const int t = threadIdx.x;
    const int v = (t < NBLK) ? partials[t] : 0;
    s[t] = v;
    __syncthreads();
    for (int o = 1; o < 256; o <<= 1) {
        const int u = (t >= o) ? s[t - o] : 0;
        __syncthreads();
        s[t] += u;
        __syncthreads();
    }
    if (t < NBLK) partials[t] = s[t] - v; // exclusive
}

__global__ __launch_bounds__(256) void k_scanC(const int* __restrict__ counts,
                                               const int* __restrict__ partials,
                                               const int* __restrict__ edges,
                                               const float* __restrict__ f,
                                               int* __restrict__ offs,
                                               int* __restrict__ cursor,
                                               float* __restrict__ g) {
    __shared__ int s[256];
    const int t = threadIdx.x;
    const int i = blockIdx.x * 256 + t;
    const int v = (i < N_NODES) ? counts[i] : 0;
    s[t] = v;
    __syncthreads();
    for (int o = 1; o < 256; o <<= 1) {
        const int u = (t >= o) ? s[t - o] : 0;
        __syncthreads();
        s[t] += u;
        __syncthreads();
    }
    if (i < N_NODES) {
        const int st = partials[blockIdx.x] + s[t] - v; // exclusive start
        offs[i] = st;
        cursor[i] = st;
        const int t2 = edges[2 * i + 1]; // quirk: f_s = f_t[sources]
        const float4 A = *reinterpret_cast<const float4*>(f + (size_t)t2 * HEADS);
        const float4 B = *reinterpret_cast<const float4*>(f + (size_t)t2 * HEADS + 4);
        *reinterpret_cast<float4*>(g + (size_t)i * HEADS) = A;
        *reinterpret_cast<float4*>(g + (size_t)i * HEADS + 4) = B;
    }
}

// ---- class-partitioned CSR fill (8 contiguous elist regions, XCD-pinned) ----
__global__ __launch_bounds__(256) void k_fill(const int* __restrict__ edges,
                                              const int* __restrict__ offs,
                                              int* __restrict__ cursor,
                                              int* __restrict__ elist) {
    const int b = blockIdx.x;
    const int cls = b & 7;
    const int e = (b >> 3) * 256 + threadIdx.x;
    if (e >= N_EDGES) return;
    const int2 st = reinterpret_cast<const int2*>(edges)[e];
    const int cl = offs[st.y] / (N_EDGES / 8); // 100000 per class
    if (cl != cls) return;
    const int p = atomicAdd(&cursor[st.y], 1);
    elist[p] = st.x;
}

// ---- single sweep, no-max softmax (safe: z <= ~8 << 88) + weighted gather ----
__global__ __launch_bounds__(256) void k_out(const __half* __restrict__ h,
                                             const int* __restrict__ elist,
                                             const float* __restrict__ f,
                                             const float* __restrict__ g,
                                             const int* __restrict__ offs, // segment START
                                             const int* __restrict__ counts,
                                             const float* __restrict__ bias,
                                             float* __restrict__ out,
                                             int nbase, int ncount) {
    const int ni = blockIdx.x * 4 + (threadIdx.x >> 6);
    if (ni >= ncount) return;
    const int n = nbase + ni;
    const int lane = threadIdx.x & 63;
    const int head = lane >> 3;
    const int c4 = lane * 4;
    const int start = offs[n];
    const int end = start + counts[n];
    const float fn = f[(size_t)n * HEADS + head];

    float d = 0.f;
    float4 acc = make_float4(0.f, 0.f, 0.f, 0.f);

    int p = start;
    for (; p + 4 <= end; p += 4) {
        const int s0 = elist[p + 0];
        const int s1 = elist[p + 1];
        const int s2 = elist[p + 2];
        const int s3 = elist[p + 3];
        const float gz0 = g[(size_t)s0 * HEADS + head];
        const float gz1 = g[(size_t)s1 * HEADS + head];
        const float gz2 = g[(size_t)s2 * HEADS + head];
        const float gz3 = g[(size_t)s3 * HEADS + head];
        const h4pk hv0 = *reinterpret_cast<const h4pk*>(h + (size_t)s0 * HU + c4);
        const h4pk hv1 = *reinterpret_cast<const h4pk*>(h + (size_t)s1 * HU + c4);
        const h4pk hv2 = *reinterpret_cast<const h4pk*>(h + (size_t)s2 * HU + c4);
        const h4pk hv3 = *reinterpret_cast<const h4pk*>(h + (size_t)s3 * HU + c4);

        float z0 = fn + gz0; z0 = (z0 > 0.f) ? z0 : LEAKY * z0;
        float z1 = fn + gz1; z1 = (z1 > 0.f) ? z1 : LEAKY * z1;
        float z2 = fn + gz2; z2 = (z2 > 0.f) ? z2 : LEAKY * z2;
        float z3 = fn + gz3; z3 = (z3 > 0.f) ? z3 : LEAKY * z3;
        const float w0 = __expf(z0);
        const float w1 = __expf(z1);
        const float w2 = __expf(z2);
        const float w3 = __expf(z3);
        d += (w0 + w1) + (w2 + w3);

        float2 fa, fb;
        fa = __half22float2(hv0.a); fb = __half22float2(hv0.b);
        acc.x += w0 * fa.x; acc.y += w0 * fa.y; acc.z += w0 * fb.x; acc.w += w0 * fb.y;
        fa = __half22float2(hv1.a); fb = __half22float2(hv1.b);
        acc.x += w1 * fa.x; acc.y += w1 * fa.y; acc.z += w1 * fb.x; acc.w += w1 * fb.y;
        fa = __half22float2(hv2.a); fb = __half22float2(hv2.b);
        acc.x += w2 * fa.x; acc.y += w2 * fa.y; acc.z += w2 * fb.x; acc.w += w2 * fb.y;
        fa = __half22float2(hv3.a); fb = __half22float2(hv3.b);
        acc.x += w3 * fa.x; acc.y += w3 * fa.y; acc.z += w3 * fb.x; acc.w += w3 * fb.y;
    }
    for (; p < end; ++p) {
        const int s = elist[p];
        float z = fn + g[(size_t)s * HEADS + head];
        z = (z > 0.f) ? z : LEAKY * z;
        const float w = __expf(z);
        const h4pk hv = *reinterpret_cast<const h4pk*>(h + (size_t)s * HU + c4);
        const float2 fa = __half22float2(hv.a);
        const float2 fb = __half22float2(hv.b);
        d += w;
        acc.x += w * fa.x;
        acc.y += w * fa.y;
        acc.z += w * fb.x;
        acc.w += w * fb.y;
    }

    const float inv = 1.f / (d + EPSV);
    const float4 b = *reinterpret_cast<const float4*>(bias + c4);
    float v;
    float4 o;
    v = acc.x * inv + b.x; o.x = (v > 0.f) ? v : expm1f(v);
    v = acc.y * inv + b.y; o.y = (v > 0.f) ? v : expm1f(v);
    v = acc.z * inv + b.z; o.z = (v > 0.f) ? v : expm1f(v);
    v = acc.w * inv + b.w; o.w = (v > 0.f) ? v : expm1f(v);
    *reinterpret_cast<float4*>(out + (size_t)n * HU + c4) = o;
}

extern "C" void kernel_launch(void* const* d_in, const int* in_sizes, int n_in,
                              void* d_out, int out_size, void* d_ws, size_t ws_size,
                              hipStream_t stream) {
    const float* x = (const float*)d_in[0];
    const int* edges = (const int*)d_in[1];
    const float* W = (const float*)d_in[2];
    const float* ka1 = (const float*)d_in[3];
    // d_in[4] = ka2: unused by the reference
    const float* bias = (const float*)d_in[5];
    float* out = (float*)d_out;

    char* ws = (char*)d_ws;
    size_t off = 0;
    auto alloc = [&](size_t bytes) -> void* {
        void* p = ws + off;
        off = (off + bytes + 255) & ~size_t(255);
        return p;
    };
    __half* h = (__half*)alloc(sizeof(__half) * (size_t)N_NODES * HU); // 25.6 MB
    __half* Wt = (__half*)alloc(sizeof(__half) * D_FEAT * HU);         // 64 KB
    float* f = (float*)alloc(sizeof(float) * N_NODES * HEADS);         // 1.6 MB
    float* g = (float*)alloc(sizeof(float) * N_NODES * HEADS);         // 1.6 MB
    int* counts = (int*)alloc(sizeof(int) * N_NODES);
    int* offs = (int*)alloc(sizeof(int) * N_NODES);
    int* cursor = (int*)alloc(sizeof(int) * N_NODES);
    int* partials = (int*)alloc(sizeof(int) * NBLK);
    int* elist = (int*)alloc(sizeof(int) * N_EDGES);                   // 3.2 MB

    hipMemsetAsync(counts, 0, sizeof(int) * N_NODES, stream);

    k_conv<<<WBLK + EBLK, 256, 0, stream>>>(W, edges, Wt, counts);
    k_gemm<<<(N_NODES + 31) / 32, 64, 0, stream>>>(x, Wt, ka1, h, f);
    k_scanA<<<NBLK, 256, 0, stream>>>(counts, partials);
    k_scanB<<<1, 256, 0, stream>>>(partials);
    k_scanC<<<NBLK, 256, 0, stream>>>(counts, partials, edges, f, offs, cursor, g);
    k_fill<<<8 * EBLK, 256, 0, stream>>>(edges, offs, cursor, elist);
    k_out<<<(25000 + 3) / 4, 256, 0, stream>>>(h, elist, f, g, offs, counts, bias, out, 0, 25000);
    k_out<<<(25000 + 3) / 4, 256, 0, stream>>>(h, elist, f, g, offs, counts, bias, out, 25000, 25000);
}

// Round 15
// 162.302 us; speedup vs baseline: 1.4007x; 1.2402x over previous
//
#include <hip/hip_runtime.h>
#include <hip/hip_fp16.h>

#define N_NODES 50000
#define N_EDGES 800000
#define D_FEAT 128
#define HEADS 8
#define UNITS 32
#define HU (HEADS * UNITS) /* 256 */
#define LEAKY 0.2f
#define EPSV 1e-7f
#define NBLK 196 /* ceil(50000/256) */
#define HSP 258 /* padded LDS row stride in halfs: bank-conflict-free */

typedef _Float16 half8 __attribute__((ext_vector_type(8)));
typedef float f32x4 __attribute__((ext_vector_type(4)));

struct h4pk { __half2 a, b; }; // 4 fp16 channels = 8 bytes

// ---- prep: W -> W^T fp16 | in-degree counts + per-edge rank ----
#define WBLK 128              /* 128*256 = 32768 = D_FEAT*HU */
#define EBLK 3125             /* 3125*256 = 800,000 = N_EDGES */
__global__ __launch_bounds__(256) void k_conv(const float* __restrict__ W,
                                              const int* __restrict__ edges,
                                              __half* __restrict__ Wt,
                                              int* __restrict__ counts,
                                              int* __restrict__ rank) {
    const int b = blockIdx.x, t = threadIdx.x;
    if (b < WBLK) {
        const int i = b * 256 + t;            // i = n*128 + k
        const int n = i >> 7, k = i & 127;
        Wt[i] = __float2half(W[k * HU + n]);  // Wt[n][k] = W[k][n]
    } else {
        const int e = (b - WBLK) * 256 + t;
        if (e < N_EDGES) {
            const int tgt = edges[2 * e + 1];
            rank[e] = atomicAdd(&counts[tgt], 1); // rank within target segment
        }
    }
}

// ---- MFMA GEMM: 1 wave / 32 rows (2 tiles), B-frag reuse, padded LDS ----
__global__ __launch_bounds__(64) void k_gemm(const float* __restrict__ x,
                                             const __half* __restrict__ Wt,
                                             const float* __restrict__ ka1,
                                             __half* __restrict__ h,
                                             float* __restrict__ f) {
    __shared__ __align__(16) _Float16 hs[16 * HSP]; // 8.1 KB
    const int l = threadIdx.x;
    const int row16 = l & 15, kg = l >> 4;
    const int rbase = blockIdx.x * 32;

    // A fragments for both tiles: fp32 loads, in-register convert
    half8 a0[4], a1[4];
    const int r0 = min(rbase + row16, N_NODES - 1);
    const int r1 = min(rbase + 16 + row16, N_NODES - 1);
    const float* xp0 = x + (size_t)r0 * D_FEAT + kg * 8;
    const float* xp1 = x + (size_t)r1 * D_FEAT + kg * 8;
#pragma unroll
    for (int ks = 0; ks < 4; ++ks) {
        const float4 u0 = *reinterpret_cast<const float4*>(xp0 + ks * 32);
        const float4 v0 = *reinterpret_cast<const float4*>(xp0 + ks * 32 + 4);
        const float4 u1 = *reinterpret_cast<const float4*>(xp1 + ks * 32);
        const float4 v1 = *reinterpret_cast<const float4*>(xp1 + ks * 32 + 4);
        half8 t0, t1;
        t0[0] = (_Float16)u0.x; t0[1] = (_Float16)u0.y; t0[2] = (_Float16)u0.z; t0[3] = (_Float16)u0.w;
        t0[4] = (_Float16)v0.x; t0[5] = (_Float16)v0.y; t0[6] = (_Float16)v0.z; t0[7] = (_Float16)v0.w;
        t1[0] = (_Float16)u1.x; t1[1] = (_Float16)u1.y; t1[2] = (_Float16)u1.z; t1[3] = (_Float16)u1.w;
        t1[4] = (_Float16)v1.x; t1[5] = (_Float16)v1.y; t1[6] = (_Float16)v1.z; t1[7] = (_Float16)v1.w;
        a0[ks] = t0; a1[ks] = t1;
    }

    f32x4 acc0[16], acc1[16];
#pragma unroll
    for (int ct = 0; ct < 16; ++ct) {
        acc0[ct] = (f32x4){0.f, 0.f, 0.f, 0.f};
        acc1[ct] = (f32x4){0.f, 0.f, 0.f, 0.f};
    }

#pragma unroll
    for (int ct = 0; ct < 16; ++ct) {
        const __half* wp = Wt + (ct * 16 + row16) * D_FEAT + kg * 8;
#pragma unroll
        for (int ks = 0; ks < 4; ++ks) {
            const half8 bf = *reinterpret_cast<const half8*>(wp + ks * 32);
            acc0[ct] = __builtin_amdgcn_mfma_f32_16x16x32_f16(a0[ks], bf, acc0[ct], 0, 0, 0);
            acc1[ct] = __builtin_amdgcn_mfma_f32_16x16x32_f16(a1[ks], bf, acc1[ct], 0, 0, 0);
        }
    }

#pragma unroll
    for (int tile = 0; tile < 2; ++tile) {
        const int rb2 = rbase + tile * 16;
#pragma unroll
        for (int ct = 0; ct < 16; ++ct) {
            const int col = ct * 16 + row16;
#pragma unroll
            for (int r = 0; r < 4; ++r) {
                const f32x4 av = tile ? acc1[ct] : acc0[ct];
                hs[(kg * 4 + r) * HSP + col] = (_Float16)av[r];
            }
        }
        __syncthreads();

#pragma unroll
        for (int j = 0; j < 8; ++j) {
            const int slot = j * 64 + l;
            const int row = slot >> 5, c8 = slot & 31;
            if (rb2 + row < N_NODES) {
                const half8 v = *reinterpret_cast<const half8*>(&hs[row * HSP + c8 * 8]);
                *reinterpret_cast<half8*>(h + (size_t)(rb2 + row) * HU + c8 * 8) = v;
            }
        }

#pragma unroll
        for (int hf = 0; hf < 2; ++hf) {
            const int o = hf * 64 + l;
            const int row = o >> 3, hd = o & 7;
            if (rb2 + row < N_NODES) {
                const _Float16* hp = &hs[row * HSP + hd * UNITS];
                const float* kp = ka1 + hd * UNITS;
                float s = 0.f;
#pragma unroll
                for (int u = 0; u < UNITS; u += 8) {
                    const half8 hv = *reinterpret_cast<const half8*>(hp + u);
                    const float4 k0 = *reinterpret_cast<const float4*>(kp + u);
                    const float4 k1 = *reinterpret_cast<const float4*>(kp + u + 4);
                    s += (float)hv[0] * k0.x + (float)hv[1] * k0.y + (float)hv[2] * k0.z + (float)hv[3] * k0.w;
                    s += (float)hv[4] * k1.x + (float)hv[5] * k1.y + (float)hv[6] * k1.z + (float)hv[7] * k1.w;
                }
                f[(size_t)rb2 * HEADS + o] = s;
            }
        }
        __syncthreads(); // hs reused by next tile
    }
}

// ---- hierarchical scan; scanC also emits g-gather ----
__global__ __launch_bounds__(256) void k_scanA(const int* __restrict__ counts,
                                               int* __restrict__ partials) {
    const int i = blockIdx.x * 256 + threadIdx.x;
    int v = (i < N_NODES) ? counts[i] : 0;
#pragma unroll
    for (int m = 32; m >= 1; m >>= 1) v += __shfl_xor(v, m);
    __shared__ int ws[4];
    if ((threadIdx.x & 63) == 0) ws[threadIdx.x >> 6] = v;
    __syncthreads();
    if (threadIdx.x == 0) partials[blockIdx.x] = ws[0] + ws[1] + ws[2] + ws[3];
}

__global__ __launch_bounds__(256) void k_scanB(int* __restrict__ partials) {
    __shared__ int s[256];
    const int t = threadIdx.x;
    const int v = (t < NBLK) ? partials[t] : 0;
    s[t] = v;
    __syncthreads();
    for (int o = 1; o < 256; o <<= 1) {
        const int u = (t >= o) ? s[t - o] : 0;
        __syncthreads();
        s[t] += u;
        __syncthreads();
    }
    if (t < NBLK) partials[t] = s[t] - v; // exclusive
}

__global__ __launch_bounds__(256) void k_scanC(const int* __restrict__ counts,
                                               const int* __restrict__ partials,
                                               const int* __restrict__ edges,
                                               const float* __restrict__ f,
                                               int* __restrict__ offs,
                                               float* __restrict__ g) {
    __shared__ int s[256];
    const int t = threadIdx.x;
    const int i = blockIdx.x * 256 + t;
    const int v = (i < N_NODES) ? counts[i] : 0;
    s[t] = v;
    __syncthreads();
    for (int o = 1; o < 256; o <<= 1) {
        const int u = (t >= o) ? s[t - o] : 0;
        __syncthreads();
        s[t] += u;
        __syncthreads();
    }
    if (i < N_NODES) {
        offs[i] = partials[blockIdx.x] + s[t] - v; // exclusive start
        const int t2 = edges[2 * i + 1]; // quirk: f_s = f_t[sources]
        const float4 A = *reinterpret_cast<const float4*>(f + (size_t)t2 * HEADS);
        const float4 B = *reinterpret_cast<const float4*>(f + (size_t)t2 * HEADS + 4);
        *reinterpret_cast<float4*>(g + (size_t)i * HEADS) = A;
        *reinterpret_cast<float4*>(g + (size_t)i * HEADS + 4) = B;
    }
}

// ---- atomic-free single-pass CSR fill: slot = offs[target] + rank[edge] ----
__global__ __launch_bounds__(256) void k_fill(const int* __restrict__ edges,
                                              const int* __restrict__ offs,
                                              const int* __restrict__ rank,
                                              int* __restrict__ elist) {
    const int e = blockIdx.x * 256 + threadIdx.x;
    if (e >= N_EDGES) return;
    const int2 st = reinterpret_cast<const int2*>(edges)[e];
    elist[offs[st.y] + rank[e]] = st.x;
}

// ---- single sweep, no-max softmax (safe: z <= ~8 << 88) + weighted gather ----
__global__ __launch_bounds__(256) void k_out(const __half* __restrict__ h,
                                             const int* __restrict__ elist,
                                             const float* __restrict__ f,
                                             const float* __restrict__ g,
                                             const int* __restrict__ offs, // segment START
                                             const int* __restrict__ counts,
                                             const float* __restrict__ bias,
                                             float* __restrict__ out) {
    const int n = blockIdx.x * 4 + (threadIdx.x >> 6);
    if (n >= N_NODES) return;
    const int lane = threadIdx.x & 63;
    const int head = lane >> 3;
    const int c4 = lane * 4;
    const int start = offs[n];
    const int end = start + counts[n];
    const float fn = f[(size_t)n * HEADS + head];

    float d = 0.f;
    float4 acc = make_float4(0.f, 0.f, 0.f, 0.f);

    int p = start;
    for (; p + 4 <= end; p += 4) {
        const int s0 = elist[p + 0];
        const int s1 = elist[p + 1];
        const int s2 = elist[p + 2];
        const int s3 = elist[p + 3];
        const float gz0 = g[(size_t)s0 * HEADS + head];
        const float gz1 = g[(size_t)s1 * HEADS + head];
        const float gz2 = g[(size_t)s2 * HEADS + head];
        const float gz3 = g[(size_t)s3 * HEADS + head];
        const h4pk hv0 = *reinterpret_cast<const h4pk*>(h + (size_t)s0 * HU + c4);
        const h4pk hv1 = *reinterpret_cast<const h4pk*>(h + (size_t)s1 * HU + c4);
        const h4pk hv2 = *reinterpret_cast<const h4pk*>(h + (size_t)s2 * HU + c4);
        const h4pk hv3 = *reinterpret_cast<const h4pk*>(h + (size_t)s3 * HU + c4);

        float z0 = fn + gz0; z0 = (z0 > 0.f) ? z0 : LEAKY * z0;
        float z1 = fn + gz1; z1 = (z1 > 0.f) ? z1 : LEAKY * z1;
        float z2 = fn + gz2; z2 = (z2 > 0.f) ? z2 : LEAKY * z2;
        float z3 = fn + gz3; z3 = (z3 > 0.f) ? z3 : LEAKY * z3;
        const float w0 = __expf(z0);
        const float w1 = __expf(z1);
        const float w2 = __expf(z2);
        const float w3 = __expf(z3);
        d += (w0 + w1) + (w2 + w3);

        float2 fa, fb;
        fa = __half22float2(hv0.a); fb = __half22float2(hv0.b);
        acc.x += w0 * fa.x; acc.y += w0 * fa.y; acc.z += w0 * fb.x; acc.w += w0 * fb.y;
        fa = __half22float2(hv1.a); fb = __half22float2(hv1.b);
        acc.x += w1 * fa.x; acc.y += w1 * fa.y; acc.z += w1 * fb.x; acc.w += w1 * fb.y;
        fa = __half22float2(hv2.a); fb = __half22float2(hv2.b);
        acc.x += w2 * fa.x; acc.y += w2 * fa.y; acc.z += w2 * fb.x; acc.w += w2 * fb.y;
        fa = __half22float2(hv3.a); fb = __half22float2(hv3.b);
        acc.x += w3 * fa.x; acc.y += w3 * fa.y; acc.z += w3 * fb.x; acc.w += w3 * fb.y;
    }
    for (; p < end; ++p) {
        const int s = elist[p];
        float z = fn + g[(size_t)s * HEADS + head];
        z = (z > 0.f) ? z : LEAKY * z;
        const float w = __expf(z);
        const h4pk hv = *reinterpret_cast<const h4pk*>(h + (size_t)s * HU + c4);
        const float2 fa = __half22float2(hv.a);
        const float2 fb = __half22float2(hv.b);
        d += w;
        acc.x += w * fa.x;
        acc.y += w * fa.y;
        acc.z += w * fb.x;
        acc.w += w * fb.y;
    }

    const float inv = 1.f / (d + EPSV);
    const float4 b = *reinterpret_cast<const float4*>(bias + c4);
    float v;
    float4 o;
    v = acc.x * inv + b.x; o.x = (v > 0.f) ? v : expm1f(v);
    v = acc.y * inv + b.y; o.y = (v > 0.f) ? v : expm1f(v);
    v = acc.z * inv + b.z; o.z = (v > 0.f) ? v : expm1f(v);
    v = acc.w * inv + b.w; o.w = (v > 0.f) ? v : expm1f(v);
    *reinterpret_cast<float4*>(out + (size_t)n * HU + c4) = o;
}

extern "C" void kernel_launch(void* const* d_in, const int* in_sizes, int n_in,
                              void* d_out, int out_size, void* d_ws, size_t ws_size,
                              hipStream_t stream) {
    const float* x = (const float*)d_in[0];
    const int* edges = (const int*)d_in[1];
    const float* W = (const float*)d_in[2];
    const float* ka1 = (const float*)d_in[3];
    // d_in[4] = ka2: unused by the reference
    const float* bias = (const float*)d_in[5];
    float* out = (float*)d_out;

    char* ws = (char*)d_ws;
    size_t off = 0;
    auto alloc = [&](size_t bytes) -> void* {
        void* p = ws + off;
        off = (off + bytes + 255) & ~size_t(255);
        return p;
    };
    __half* h = (__half*)alloc(sizeof(__half) * (size_t)N_NODES * HU); // 25.6 MB
    __half* Wt = (__half*)alloc(sizeof(__half) * D_FEAT * HU);         // 64 KB
    float* f = (float*)alloc(sizeof(float) * N_NODES * HEADS);         // 1.6 MB
    float* g = (float*)alloc(sizeof(float) * N_NODES * HEADS);         // 1.6 MB
    int* counts = (int*)alloc(sizeof(int) * N_NODES);
    int* offs = (int*)alloc(sizeof(int) * N_NODES);
    int* partials = (int*)alloc(sizeof(int) * NBLK);
    int* rank = (int*)alloc(sizeof(int) * N_EDGES);                    // 3.2 MB
    int* elist = (int*)alloc(sizeof(int) * N_EDGES);                   // 3.2 MB

    hipMemsetAsync(counts, 0, sizeof(int) * N_NODES, stream);

    k_conv<<<WBLK + EBLK, 256, 0, stream>>>(W, edges, Wt, counts, rank);
    k_gemm<<<(N_NODES + 31) / 32, 64, 0, stream>>>(x, Wt, ka1, h, f);
    k_scanA<<<NBLK, 256, 0, stream>>>(counts, partials);
    k_scanB<<<1, 256, 0, stream>>>(partials);
    k_scanC<<<NBLK, 256, 0, stream>>>(counts, partials, edges, f, offs, g);
    k_fill<<<EBLK, 256, 0, stream>>>(edges, offs, rank, elist);
    k_out<<<(N_NODES + 3) / 4, 256, 0, stream>>>(h, elist, f, g, offs, counts, bias, out);
}

// Round 16
// 150.521 us; speedup vs baseline: 1.5104x; 1.0783x over previous
//
#include <hip/hip_runtime.h>
#include <hip/hip_fp16.h>

#define N_NODES 50000
#define N_EDGES 800000
#define D_FEAT 128
#define HEADS 8
#define UNITS 32
#define HU (HEADS * UNITS) /* 256 */
#define LEAKY 0.2f
#define EPSV 1e-7f
#define NBLK 196 /* ceil(50000/256) */
#define HSP 258 /* padded LDS row stride in halfs: bank-conflict-free */

typedef _Float16 half8 __attribute__((ext_vector_type(8)));
typedef float f32x4 __attribute__((ext_vector_type(4)));

struct h4pk { __half2 a, b; }; // 4 fp16 channels = 8 bytes

// ---- W -> W^T fp16 (tiny, runs first so k_big's gemm branch has Wt) ----
#define WBLK 128 /* 128*256 = 32768 = D_FEAT*HU */
__global__ __launch_bounds__(256) void k_wt(const float* __restrict__ W,
                                            __half* __restrict__ Wt) {
    const int i = blockIdx.x * 256 + threadIdx.x; // i = n*128 + k
    const int n = i >> 7, k = i & 127;
    Wt[i] = __float2half(W[k * HU + n]);          // Wt[n][k] = W[k][n]
}

// ---- BIG: gemm blocks [0,GB) co-run with count/rank blocks [GB,GB+CB).
// gemm branch: R15's clean 64-thread 2-tile MFMA kernel (verbatim).
// count branch: per-edge in-degree count + rank capture (atomic pipe —
// hides under gemm's MFMA/VMEM work).
#define GB 1563  /* ceil(50000/32) gemm blocks */
#define CB 12500 /* 800000/64 count blocks */
__global__ __launch_bounds__(64) void k_big(const float* __restrict__ x,
                                            const __half* __restrict__ Wt,
                                            const float* __restrict__ ka1,
                                            const int* __restrict__ edges,
                                            int* __restrict__ counts,
                                            int* __restrict__ rank,
                                            __half* __restrict__ h,
                                            float* __restrict__ f) {
    __shared__ __align__(16) _Float16 hs[16 * HSP]; // 8.1 KB
    const int l = threadIdx.x;
    if (blockIdx.x >= GB) {
        // ---- count/rank branch ----
        const int e = (blockIdx.x - GB) * 64 + l;
        if (e < N_EDGES) {
            const int tgt = edges[2 * e + 1];
            rank[e] = atomicAdd(&counts[tgt], 1);
        }
        return;
    }
    // ---- gemm branch (R15 verbatim) ----
    const int row16 = l & 15, kg = l >> 4;
    const int rbase = blockIdx.x * 32;

    half8 a0[4], a1[4];
    const int r0 = min(rbase + row16, N_NODES - 1);
    const int r1 = min(rbase + 16 + row16, N_NODES - 1);
    const float* xp0 = x + (size_t)r0 * D_FEAT + kg * 8;
    const float* xp1 = x + (size_t)r1 * D_FEAT + kg * 8;
#pragma unroll
    for (int ks = 0; ks < 4; ++ks) {
        const float4 u0 = *reinterpret_cast<const float4*>(xp0 + ks * 32);
        const float4 v0 = *reinterpret_cast<const float4*>(xp0 + ks * 32 + 4);
        const float4 u1 = *reinterpret_cast<const float4*>(xp1 + ks * 32);
        const float4 v1 = *reinterpret_cast<const float4*>(xp1 + ks * 32 + 4);
        half8 t0, t1;
        t0[0] = (_Float16)u0.x; t0[1] = (_Float16)u0.y; t0[2] = (_Float16)u0.z; t0[3] = (_Float16)u0.w;
        t0[4] = (_Float16)v0.x; t0[5] = (_Float16)v0.y; t0[6] = (_Float16)v0.z; t0[7] = (_Float16)v0.w;
        t1[0] = (_Float16)u1.x; t1[1] = (_Float16)u1.y; t1[2] = (_Float16)u1.z; t1[3] = (_Float16)u1.w;
        t1[4] = (_Float16)v1.x; t1[5] = (_Float16)v1.y; t1[6] = (_Float16)v1.z; t1[7] = (_Float16)v1.w;
        a0[ks] = t0; a1[ks] = t1;
    }

    f32x4 acc0[16], acc1[16];
#pragma unroll
    for (int ct = 0; ct < 16; ++ct) {
        acc0[ct] = (f32x4){0.f, 0.f, 0.f, 0.f};
        acc1[ct] = (f32x4){0.f, 0.f, 0.f, 0.f};
    }

#pragma unroll
    for (int ct = 0; ct < 16; ++ct) {
        const __half* wp = Wt + (ct * 16 + row16) * D_FEAT + kg * 8;
#pragma unroll
        for (int ks = 0; ks < 4; ++ks) {
            const half8 bf = *reinterpret_cast<const half8*>(wp + ks * 32);
            acc0[ct] = __builtin_amdgcn_mfma_f32_16x16x32_f16(a0[ks], bf, acc0[ct], 0, 0, 0);
            acc1[ct] = __builtin_amdgcn_mfma_f32_16x16x32_f16(a1[ks], bf, acc1[ct], 0, 0, 0);
        }
    }

#pragma unroll
    for (int tile = 0; tile < 2; ++tile) {
        const int rb2 = rbase + tile * 16;
#pragma unroll
        for (int ct = 0; ct < 16; ++ct) {
            const int col = ct * 16 + row16;
#pragma unroll
            for (int r = 0; r < 4; ++r) {
                const f32x4 av = tile ? acc1[ct] : acc0[ct];
                hs[(kg * 4 + r) * HSP + col] = (_Float16)av[r];
            }
        }
        __syncthreads();

#pragma unroll
        for (int j = 0; j < 8; ++j) {
            const int slot = j * 64 + l;
            const int row = slot >> 5, c8 = slot & 31;
            if (rb2 + row < N_NODES) {
                const half8 v = *reinterpret_cast<const half8*>(&hs[row * HSP + c8 * 8]);
                *reinterpret_cast<half8*>(h + (size_t)(rb2 + row) * HU + c8 * 8) = v;
            }
        }

#pragma unroll
        for (int hf = 0; hf < 2; ++hf) {
            const int o = hf * 64 + l;
            const int row = o >> 3, hd = o & 7;
            if (rb2 + row < N_NODES) {
                const _Float16* hp = &hs[row * HSP + hd * UNITS];
                const float* kp = ka1 + hd * UNITS;
                float s = 0.f;
#pragma unroll
                for (int u = 0; u < UNITS; u += 8) {
                    const half8 hv = *reinterpret_cast<const half8*>(hp + u);
                    const float4 k0 = *reinterpret_cast<const float4*>(kp + u);
                    const float4 k1 = *reinterpret_cast<const float4*>(kp + u + 4);
                    s += (float)hv[0] * k0.x + (float)hv[1] * k0.y + (float)hv[2] * k0.z + (float)hv[3] * k0.w;
                    s += (float)hv[4] * k1.x + (float)hv[5] * k1.y + (float)hv[6] * k1.z + (float)hv[7] * k1.w;
                }
                f[(size_t)rb2 * HEADS + o] = s;
            }
        }
        __syncthreads(); // hs reused by next tile
    }
}

// ---- hierarchical scan; scanC also emits g-gather ----
__global__ __launch_bounds__(256) void k_scanA(const int* __restrict__ counts,
                                               int* __restrict__ partials) {
    const int i = blockIdx.x * 256 + threadIdx.x;
    int v = (i < N_NODES) ? counts[i] : 0;
#pragma unroll
    for (int m = 32; m >= 1; m >>= 1) v += __shfl_xor(v, m);
    __shared__ int ws[4];
    if ((threadIdx.x & 63) == 0) ws[threadIdx.x >> 6] = v;
    __syncthreads();
    if (threadIdx.x == 0) partials[blockIdx.x] = ws[0] + ws[1] + ws[2] + ws[3];
}

__global__ __launch_bounds__(256) void k_scanB(int* __restrict__ partials) {
    __shared__ int s[256];
    const int t = threadIdx.x;
    const int v = (t < NBLK) ? partials[t] : 0;
    s[t] = v;
    __syncthreads();
    for (int o = 1; o < 256; o <<= 1) {
        const int u = (t >= o) ? s[t - o] : 0;
        __syncthreads();
        s[t] += u;
        __syncthreads();
    }
    if (t < NBLK) partials[t] = s[t] - v; // exclusive
}

__global__ __launch_bounds__(256) void k_scanC(const int* __restrict__ counts,
                                               const int* __restrict__ partials,
                                               const int* __restrict__ edges,
                                               const float* __restrict__ f,
                                               int* __restrict__ offs,
                                               float* __restrict__ g) {
    __shared__ int s[256];
    const int t = threadIdx.x;
    const int i = blockIdx.x * 256 + t;
    const int v = (i < N_NODES) ? counts[i] : 0;
    s[t] = v;
    __syncthreads();
    for (int o = 1; o < 256; o <<= 1) {
        const int u = (t >= o) ? s[t - o] : 0;
        __syncthreads();
        s[t] += u;
        __syncthreads();
    }
    if (i < N_NODES) {
        offs[i] = partials[blockIdx.x] + s[t] - v; // exclusive start
        const int t2 = edges[2 * i + 1]; // quirk: f_s = f_t[sources]
        const float4 A = *reinterpret_cast<const float4*>(f + (size_t)t2 * HEADS);
        const float4 B = *reinterpret_cast<const float4*>(f + (size_t)t2 * HEADS + 4);
        *reinterpret_cast<float4*>(g + (size_t)i * HEADS) = A;
        *reinterpret_cast<float4*>(g + (size_t)i * HEADS + 4) = B;
    }
}

// ---- atomic-free single-pass CSR fill: slot = offs[target] + rank[edge] ----
#define EBLK 3125 /* 3125*256 = 800,000 */
__global__ __launch_bounds__(256) void k_fill(const int* __restrict__ edges,
                                              const int* __restrict__ offs,
                                              const int* __restrict__ rank,
                                              int* __restrict__ elist) {
    const int e = blockIdx.x * 256 + threadIdx.x;
    if (e >= N_EDGES) return;
    const int2 st = reinterpret_cast<const int2*>(edges)[e];
    elist[offs[st.y] + rank[e]] = st.x;
}

// ---- single sweep, no-max softmax (safe: z <= ~8 << 88) + weighted gather ----
__global__ __launch_bounds__(256) void k_out(const __half* __restrict__ h,
                                             const int* __restrict__ elist,
                                             const float* __restrict__ f,
                                             const float* __restrict__ g,
                                             const int* __restrict__ offs, // segment START
                                             const int* __restrict__ counts,
                                             const float* __restrict__ bias,
                                             float* __restrict__ out) {
    const int n = blockIdx.x * 4 + (threadIdx.x >> 6);
    if (n >= N_NODES) return;
    const int lane = threadIdx.x & 63;
    const int head = lane >> 3;
    const int c4 = lane * 4;
    const int start = offs[n];
    const int end = start + counts[n];
    const float fn = f[(size_t)n * HEADS + head];

    float d = 0.f;
    float4 acc = make_float4(0.f, 0.f, 0.f, 0.f);

    int p = start;
    for (; p + 4 <= end; p += 4) {
        const int s0 = elist[p + 0];
        const int s1 = elist[p + 1];
        const int s2 = elist[p + 2];
        const int s3 = elist[p + 3];
        const float gz0 = g[(size_t)s0 * HEADS + head];
        const float gz1 = g[(size_t)s1 * HEADS + head];
        const float gz2 = g[(size_t)s2 * HEADS + head];
        const float gz3 = g[(size_t)s3 * HEADS + head];
        const h4pk hv0 = *reinterpret_cast<const h4pk*>(h + (size_t)s0 * HU + c4);
        const h4pk hv1 = *reinterpret_cast<const h4pk*>(h + (size_t)s1 * HU + c4);
        const h4pk hv2 = *reinterpret_cast<const h4pk*>(h + (size_t)s2 * HU + c4);
        const h4pk hv3 = *reinterpret_cast<const h4pk*>(h + (size_t)s3 * HU + c4);

        float z0 = fn + gz0; z0 = (z0 > 0.f) ? z0 : LEAKY * z0;
        float z1 = fn + gz1; z1 = (z1 > 0.f) ? z1 : LEAKY * z1;
        float z2 = fn + gz2; z2 = (z2 > 0.f) ? z2 : LEAKY * z2;
        float z3 = fn + gz3; z3 = (z3 > 0.f) ? z3 : LEAKY * z3;
        const float w0 = __expf(z0);
        const float w1 = __expf(z1);
        const float w2 = __expf(z2);
        const float w3 = __expf(z3);
        d += (w0 + w1) + (w2 + w3);

        float2 fa, fb;
        fa = __half22float2(hv0.a); fb = __half22float2(hv0.b);
        acc.x += w0 * fa.x; acc.y += w0 * fa.y; acc.z += w0 * fb.x; acc.w += w0 * fb.y;
        fa = __half22float2(hv1.a); fb = __half22float2(hv1.b);
        acc.x += w1 * fa.x; acc.y += w1 * fa.y; acc.z += w1 * fb.x; acc.w += w1 * fb.y;
        fa = __half22float2(hv2.a); fb = __half22float2(hv2.b);
        acc.x += w2 * fa.x; acc.y += w2 * fa.y; acc.z += w2 * fb.x; acc.w += w2 * fb.y;
        fa = __half22float2(hv3.a); fb = __half22float2(hv3.b);
        acc.x += w3 * fa.x; acc.y += w3 * fa.y; acc.z += w3 * fb.x; acc.w += w3 * fb.y;
    }
    for (; p < end; ++p) {
        const int s = elist[p];
        float z = fn + g[(size_t)s * HEADS + head];
        z = (z > 0.f) ? z : LEAKY * z;
        const float w = __expf(z);
        const h4pk hv = *reinterpret_cast<const h4pk*>(h + (size_t)s * HU + c4);
        const float2 fa = __half22float2(hv.a);
        const float2 fb = __half22float2(hv.b);
        d += w;
        acc.x += w * fa.x;
        acc.y += w * fa.y;
        acc.z += w * fb.x;
        acc.w += w * fb.y;
    }

    const float inv = 1.f / (d + EPSV);
    const float4 b = *reinterpret_cast<const float4*>(bias + c4);
    float v;
    float4 o;
    v = acc.x * inv + b.x; o.x = (v > 0.f) ? v : expm1f(v);
    v = acc.y * inv + b.y; o.y = (v > 0.f) ? v : expm1f(v);
    v = acc.z * inv + b.z; o.z = (v > 0.f) ? v : expm1f(v);
    v = acc.w * inv + b.w; o.w = (v > 0.f) ? v : expm1f(v);
    *reinterpret_cast<float4*>(out + (size_t)n * HU + c4) = o;
}

extern "C" void kernel_launch(void* const* d_in, const int* in_sizes, int n_in,
                              void* d_out, int out_size, void* d_ws, size_t ws_size,
                              hipStream_t stream) {
    const float* x = (const float*)d_in[0];
    const int* edges = (const int*)d_in[1];
    const float* W = (const float*)d_in[2];
    const float* ka1 = (const float*)d_in[3];
    // d_in[4] = ka2: unused by the reference
    const float* bias = (const float*)d_in[5];
    float* out = (float*)d_out;

    char* ws = (char*)d_ws;
    size_t off = 0;
    auto alloc = [&](size_t bytes) -> void* {
        void* p = ws + off;
        off = (off + bytes + 255) & ~size_t(255);
        return p;
    };
    __half* h = (__half*)alloc(sizeof(__half) * (size_t)N_NODES * HU); // 25.6 MB
    __half* Wt = (__half*)alloc(sizeof(__half) * D_FEAT * HU);         // 64 KB
    float* f = (float*)alloc(sizeof(float) * N_NODES * HEADS);         // 1.6 MB
    float* g = (float*)alloc(sizeof(float) * N_NODES * HEADS);         // 1.6 MB
    int* counts = (int*)alloc(sizeof(int) * N_NODES);
    int* offs = (int*)alloc(sizeof(int) * N_NODES);
    int* partials = (int*)alloc(sizeof(int) * NBLK);
    int* rank = (int*)alloc(sizeof(int) * N_EDGES);                    // 3.2 MB
    int* elist = (int*)alloc(sizeof(int) * N_EDGES);                   // 3.2 MB

    hipMemsetAsync(counts, 0, sizeof(int) * N_NODES, stream);

    k_wt<<<WBLK, 256, 0, stream>>>(W, Wt);
    k_big<<<GB + CB, 64, 0, stream>>>(x, Wt, ka1, edges, counts, rank, h, f);
    k_scanA<<<NBLK, 256, 0, stream>>>(counts, partials);
    k_scanB<<<1, 256, 0, stream>>>(partials);
    k_scanC<<<NBLK, 256, 0, stream>>>(counts, partials, edges, f, offs, g);
    k_fill<<<EBLK, 256, 0, stream>>>(edges, offs, rank, elist);
    k_out<<<(N_NODES + 3) / 4, 256, 0, stream>>>(h, elist, f, g, offs, counts, bias, out);
}